// Round 9
// baseline (574.757 us; speedup 1.0000x reference)
//
#include <hip/hip_runtime.h>
#include <stdint.h>

#define T_SEQ   2048
#define DMODEL  1024
#define NHEADS  16
#define HDIM    64
#define BATCH   4
#define MROWS   (BATCH * T_SEQ)   // 8192

typedef __attribute__((ext_vector_type(4))) short bf16x4;
typedef __attribute__((ext_vector_type(8))) short bf16x8;
typedef __attribute__((ext_vector_type(4))) float f32x4;

__device__ __forceinline__ float b2f(unsigned short u) {
    union { unsigned int i; float f; } x;
    x.i = ((unsigned int)u) << 16;
    return x.f;
}

__device__ __forceinline__ unsigned short f2b(float f) {
    union { float f; unsigned int i; } x;
    x.f = f;
    unsigned int r = x.i + 0x7FFFu + ((x.i >> 16) & 1u);  // RNE
    return (unsigned short)(r >> 16);
}

// ---------------------------------------------------------------------------
// fp32 -> bf16 elementwise convert
// ---------------------------------------------------------------------------
__global__ __launch_bounds__(256) void cvt_bf16(
    const float* __restrict__ in, unsigned short* __restrict__ out, int n)
{
    const int i = (blockIdx.x * 256 + threadIdx.x) * 4;
    if (i + 3 < n) {
        const float4 v = *(const float4*)(in + i);
        ushort4 o;
        o.x = f2b(v.x); o.y = f2b(v.y); o.z = f2b(v.z); o.w = f2b(v.w);
        *(ushort4*)(out + i) = o;
    }
}

// ---------------------------------------------------------------------------
// fp32 [K][N] -> bf16 [N][K] transpose+convert, 32x32 LDS tile
// ---------------------------------------------------------------------------
__global__ __launch_bounds__(256) void cvt_tr(
    const float* __restrict__ W, unsigned short* __restrict__ WT, int K, int N)
{
    __shared__ unsigned short s[32][33];
    const int n0 = blockIdx.x * 32, k0 = blockIdx.y * 32;
    const int tx = threadIdx.x & 31, ty = threadIdx.x >> 5;   // ty 0..7
    #pragma unroll
    for (int i = 0; i < 4; i++)
        s[ty + 8 * i][tx] = f2b(W[(size_t)(k0 + ty + 8 * i) * N + n0 + tx]);
    __syncthreads();
    #pragma unroll
    for (int i = 0; i < 4; i++)
        WT[(size_t)(n0 + ty + 8 * i) * K + k0 + tx] = s[tx][ty + 8 * i];
}

// ---------------------------------------------------------------------------
// bf16 MFMA GEMM: C[M][N] = A[M][Kd] * BT[N][Kd]^T + bias[N]
// 128x128 tile, BK=32, 256 thr = 4 waves (2x2), each wave 64x64 = 4x4 MFMAs.
// (unchanged from R5)
// ---------------------------------------------------------------------------
__global__ __launch_bounds__(256) void gemm_mfma(
    const unsigned short* __restrict__ A,
    const unsigned short* __restrict__ BT,
    const float* __restrict__ bias,
    int N, int Kd, int mode,
    unsigned short* __restrict__ Oq,
    unsigned short* __restrict__ Ok,
    unsigned short* __restrict__ Ov,
    float* __restrict__ Of)
{
    __shared__ __align__(16) unsigned short aS[128 * 32];
    __shared__ __align__(16) unsigned short bS[128 * 32];

    const int tid  = threadIdx.x;
    const int lane = tid & 63;
    const int wave = tid >> 6;
    const int row  = lane & 15;
    const int quad = lane >> 4;
    const int wm   = wave >> 1;
    const int wn   = wave & 1;
    const int m0   = blockIdx.y * 128;
    const int n0   = blockIdx.x * 128;

    const int srow  = lane >> 2;
    const int kq    = lane & 3;
    const int sslot = (kq + (srow >> 1)) & 3;
    const int soffA = wave * 512 + srow * 32 + sslot * 8;
    const int frd = row * 32 + (((quad + (row >> 1)) & 3) * 8);

    f32x4 acc[4][4];
    const f32x4 z = {0.f, 0.f, 0.f, 0.f};
    #pragma unroll
    for (int i = 0; i < 4; i++)
        #pragma unroll
        for (int j = 0; j < 4; j++) acc[i][j] = z;

    for (int k0 = 0; k0 < Kd; k0 += 32) {
        const uint4 a0 = *(const uint4*)(A  + (size_t)(m0 + wave * 16      + srow) * Kd + k0 + kq * 8);
        const uint4 a1 = *(const uint4*)(A  + (size_t)(m0 + (wave + 4) * 16 + srow) * Kd + k0 + kq * 8);
        const uint4 b0 = *(const uint4*)(BT + (size_t)(n0 + wave * 16      + srow) * Kd + k0 + kq * 8);
        const uint4 b1 = *(const uint4*)(BT + (size_t)(n0 + (wave + 4) * 16 + srow) * Kd + k0 + kq * 8);

        __syncthreads();
        *(uint4*)(aS + soffA)        = a0;
        *(uint4*)(aS + soffA + 2048) = a1;
        *(uint4*)(bS + soffA)        = b0;
        *(uint4*)(bS + soffA + 2048) = b1;
        __syncthreads();

        bf16x8 af[4], bf[4];
        #pragma unroll
        for (int t = 0; t < 4; t++) {
            af[t] = *(const bf16x8*)(aS + (wm * 4 + t) * 512 + frd);
            bf[t] = *(const bf16x8*)(bS + (wn * 4 + t) * 512 + frd);
        }
        #pragma unroll
        for (int i = 0; i < 4; i++)
            #pragma unroll
            for (int j = 0; j < 4; j++)
                acc[i][j] = __builtin_amdgcn_mfma_f32_16x16x32_bf16(af[i], bf[j], acc[i][j], 0, 0, 0);
    }

    if (mode == 0) {
        #pragma unroll
        for (int j = 0; j < 4; j++) {
            const int n  = n0 + wn * 64 + j * 16 + row;
            const float bi = bias[n];
            const int which = n >> 10;
            const int rem   = n & 1023;
            const int h     = rem >> 6;
            const int d     = rem & 63;
            #pragma unroll
            for (int i = 0; i < 4; i++) {
                const int mbase = m0 + wm * 64 + i * 16 + quad * 4;
                #pragma unroll
                for (int r = 0; r < 4; r++) {
                    const int m = mbase + r;
                    const int b = m >> 11;
                    const int t = m & 2047;
                    const int bh = b * NHEADS + h;
                    const float v = acc[i][j][r] + bi;
                    if (which == 0) {
                        Oq[((size_t)bh * T_SEQ + t) * HDIM + d] = f2b(v * 0.125f);
                    } else if (which == 1) {
                        Ok[((size_t)bh * T_SEQ + t) * HDIM + d] = f2b(v);
                    } else {
                        Ov[((size_t)bh * HDIM + d) * T_SEQ + t] = f2b(v);
                    }
                }
            }
        }
    } else {
        #pragma unroll
        for (int j = 0; j < 4; j++) {
            const int n  = n0 + wn * 64 + j * 16 + row;
            const float bi = bias[n];
            #pragma unroll
            for (int i = 0; i < 4; i++) {
                const int mbase = m0 + wm * 64 + i * 16 + quad * 4;
                #pragma unroll
                for (int r = 0; r < 4; r++)
                    Of[(size_t)(mbase + r) * N + n] = acc[i][j][r] + bi;
            }
        }
    }
}

// ---------------------------------------------------------------------------
// MFMA flash attention: one WORKGROUP per q-tile pair (p, 127-p); its 4 waves
// split the key range strided (wave w: kb = w*64, step 256). Each wave keeps
// R7's online-softmax state (m, l, o); partials merge in LDS at the end with
// the exact flash merge: M = max m_w; L = sum l_w e^{m_w-M};
// o = sum o_w e^{m_w-M}; out = o/L. Uniform work per WG by pair construction;
// 4096 WGs = 16384 waves (4x R7 supply).
// ---------------------------------------------------------------------------
__global__ __launch_bounds__(256) void attn_mfma(
    const unsigned short* __restrict__ Q,   // [bh][t][64] bf16 (scaled)
    const unsigned short* __restrict__ K,   // [bh][t][64] bf16
    const unsigned short* __restrict__ VT,  // [bh][64][T] bf16
    unsigned short* __restrict__ Out)       // [B*T][DMODEL] bf16
{
    __shared__ float oS[2][4][16][64];   // [tile H/L][wave][q][d]  32 KiB
    __shared__ float mS[2][4][16];
    __shared__ float lS[2][4][16];

    const int lane = threadIdx.x & 63;
    const int wave = threadIdx.x >> 6;
    const int row  = lane & 15;
    const int quad = lane >> 4;

    const int bh = blockIdx.x;
    const int b  = bh >> 4;
    const int h  = bh & 15;
    const int p  = blockIdx.y;            // 0..63
    const int q0L = 16 * p;
    const int q0H = 16 * (127 - p);

    const size_t qkbase = (size_t)bh * T_SEQ * HDIM;
    const size_t vtbase = (size_t)bh * HDIM * T_SEQ;

    const unsigned short* qpL = Q + qkbase + (size_t)(q0L + row) * HDIM + quad * 8;
    const bf16x8 qL0 = *(const bf16x8*)qpL;
    const bf16x8 qL1 = *(const bf16x8*)(qpL + 32);
    const unsigned short* qpH = Q + qkbase + (size_t)(q0H + row) * HDIM + quad * 8;
    const bf16x8 qH0 = *(const bf16x8*)qpH;
    const bf16x8 qH1 = *(const bf16x8*)(qpH + 32);

    const f32x4 z = {0.f, 0.f, 0.f, 0.f};
    f32x4 oL[4] = {z, z, z, z};
    f32x4 oH[4] = {z, z, z, z};
    float mL = -1e30f, lL = 0.f, mH = -1e30f, lH = 0.f;

    const int kendL = q0L + 16;
    const int kendH = q0H + 16;

    for (int kb = wave * 64; kb < kendH; kb += 256) {
        const bool doL = (kb < kendL);     // wave-uniform

        // ---- QK^T for both tiles, K frags loaded once ----
        f32x4 sH[4], sL[4];
        #pragma unroll
        for (int s = 0; s < 4; s++) {
            const unsigned short* kp = K + qkbase + (size_t)(kb + s * 16 + row) * HDIM + quad * 8;
            const bf16x8 kf0 = *(const bf16x8*)kp;
            const bf16x8 kf1 = *(const bf16x8*)(kp + 32);
            f32x4 t = z;
            t = __builtin_amdgcn_mfma_f32_16x16x32_bf16(kf0, qH0, t, 0, 0, 0);
            t = __builtin_amdgcn_mfma_f32_16x16x32_bf16(kf1, qH1, t, 0, 0, 0);
            sH[s] = t;
            if (doL) {
                f32x4 u = z;
                u = __builtin_amdgcn_mfma_f32_16x16x32_bf16(kf0, qL0, u, 0, 0, 0);
                u = __builtin_amdgcn_mfma_f32_16x16x32_bf16(kf1, qL1, u, 0, 0, 0);
                sL[s] = u;
            }
        }

        // ---- causal masks ----
        #pragma unroll
        for (int s = 0; s < 4; s++) {
            const int kbs = kb + s * 16;
            if (kbs > q0H) {
                #pragma unroll
                for (int r = 0; r < 4; r++) sH[s][r] = -1e30f;
            } else if (kbs == q0H) {
                #pragma unroll
                for (int r = 0; r < 4; r++)
                    if (quad * 4 + r > row) sH[s][r] = -1e30f;
            }
        }
        if (doL) {
            #pragma unroll
            for (int s = 0; s < 4; s++) {
                const int kbs = kb + s * 16;
                if (kbs > q0L) {
                    #pragma unroll
                    for (int r = 0; r < 4; r++) sL[s][r] = -1e30f;
                } else if (kbs == q0L) {
                    #pragma unroll
                    for (int r = 0; r < 4; r++)
                        if (quad * 4 + r > row) sL[s][r] = -1e30f;
                }
            }
        }

        // ---- online softmax, tile H ----
        bf16x4 pfH[4];
        {
            float mc = -1e30f;
            #pragma unroll
            for (int s = 0; s < 4; s++)
                #pragma unroll
                for (int r = 0; r < 4; r++) mc = fmaxf(mc, sH[s][r]);
            mc = fmaxf(mc, __shfl_xor(mc, 16));
            mc = fmaxf(mc, __shfl_xor(mc, 32));
            const float mn    = fmaxf(mH, mc);
            const float alpha = __expf(mH - mn);
            float ps = 0.f;
            #pragma unroll
            for (int s = 0; s < 4; s++) {
                #pragma unroll
                for (int r = 0; r < 4; r++) {
                    const unsigned short pb = f2b(__expf(sH[s][r] - mn));
                    pfH[s][r] = (short)pb;
                    ps += b2f(pb);
                }
            }
            ps += __shfl_xor(ps, 16);
            ps += __shfl_xor(ps, 32);
            lH = lH * alpha + ps;
            mH = mn;
            #pragma unroll
            for (int dt = 0; dt < 4; dt++)
                #pragma unroll
                for (int r = 0; r < 4; r++) oH[dt][r] *= alpha;
        }

        // ---- online softmax, tile L ----
        bf16x4 pfL[4];
        if (doL) {
            float mc = -1e30f;
            #pragma unroll
            for (int s = 0; s < 4; s++)
                #pragma unroll
                for (int r = 0; r < 4; r++) mc = fmaxf(mc, sL[s][r]);
            mc = fmaxf(mc, __shfl_xor(mc, 16));
            mc = fmaxf(mc, __shfl_xor(mc, 32));
            const float mn    = fmaxf(mL, mc);
            const float alpha = __expf(mL - mn);
            float ps = 0.f;
            #pragma unroll
            for (int s = 0; s < 4; s++) {
                #pragma unroll
                for (int r = 0; r < 4; r++) {
                    const unsigned short pb = f2b(__expf(sL[s][r] - mn));
                    pfL[s][r] = (short)pb;
                    ps += b2f(pb);
                }
            }
            ps += __shfl_xor(ps, 16);
            ps += __shfl_xor(ps, 32);
            lL = lL * alpha + ps;
            mL = mn;
            #pragma unroll
            for (int dt = 0; dt < 4; dt++)
                #pragma unroll
                for (int r = 0; r < 4; r++) oL[dt][r] *= alpha;
        }

        // ---- PV for both tiles, V frags loaded once ----
        #pragma unroll
        for (int s = 0; s < 4; s++) {
            #pragma unroll
            for (int dt = 0; dt < 4; dt++) {
                const unsigned short* vp = VT + vtbase + (size_t)(dt * 16 + row) * T_SEQ + kb + s * 16 + quad * 4;
                const bf16x4 vf = *(const bf16x4*)vp;
                oH[dt] = __builtin_amdgcn_mfma_f32_16x16x16bf16_1k(vf, pfH[s], oH[dt], 0, 0, 0);
                if (doL)
                    oL[dt] = __builtin_amdgcn_mfma_f32_16x16x16bf16_1k(vf, pfL[s], oL[dt], 0, 0, 0);
            }
        }
    }

    // ---- write per-wave partials to LDS ----
    #pragma unroll
    for (int dt = 0; dt < 4; dt++) {
        #pragma unroll
        for (int r = 0; r < 4; r++) {
            oS[0][wave][row][dt * 16 + quad * 4 + r] = oH[dt][r];
            oS[1][wave][row][dt * 16 + quad * 4 + r] = oL[dt][r];
        }
    }
    if (quad == 0) {
        mS[0][wave][row] = mH; lS[0][wave][row] = lH;
        mS[1][wave][row] = mL; lS[1][wave][row] = lL;
    }
    __syncthreads();

    // ---- merge partials + store: tid -> (tile, d-half, q, d-group) ----
    {
        const int tile = threadIdx.x >> 7;          // 0 = H, 1 = L
        const int half = (threadIdx.x >> 6) & 1;
        const int q    = lane & 15;
        const int d0   = half * 32 + (lane >> 4) * 8;

        float mw[4];
        float M = -1e30f;
        #pragma unroll
        for (int w = 0; w < 4; w++) {
            mw[w] = mS[tile][w][q];
            M = fmaxf(M, mw[w]);
        }
        float ew[4];
        float L = 0.f;
        #pragma unroll
        for (int w = 0; w < 4; w++) {
            ew[w] = __expf(mw[w] - M);
            L += lS[tile][w][q] * ew[w];
        }
        const float rl = 1.f / L;

        float res[8];
        #pragma unroll
        for (int j = 0; j < 8; j++) {
            float acc = 0.f;
            #pragma unroll
            for (int w = 0; w < 4; w++)
                acc += oS[tile][w][q][d0 + j] * ew[w];
            res[j] = acc * rl;
        }

        const int q0X = tile ? q0L : q0H;
        unsigned short* op = Out + ((size_t)(b * T_SEQ + q0X + q)) * DMODEL + h * HDIM + d0;
        ushort4 pk0, pk1;
        pk0.x = f2b(res[0]); pk0.y = f2b(res[1]); pk0.z = f2b(res[2]); pk0.w = f2b(res[3]);
        pk1.x = f2b(res[4]); pk1.y = f2b(res[5]); pk1.z = f2b(res[6]); pk1.w = f2b(res[7]);
        *(ushort4*)op       = pk0;
        *(ushort4*)(op + 4) = pk1;
    }
}

extern "C" void kernel_launch(void* const* d_in, const int* in_sizes, int n_in,
                              void* d_out, int out_size, void* d_ws, size_t ws_size,
                              hipStream_t stream)
{
    const float* x    = (const float*)d_in[0];
    const float* Wqkv = (const float*)d_in[1];
    const float* bqkv = (const float*)d_in[2];
    const float* Wout = (const float*)d_in[3];
    const float* bout = (const float*)d_in[4];
    float* out = (float*)d_out;

    // workspace (MiB offsets): xb 0..16 | WqkvT 16..22 | WoutT 22..24 |
    // Qb 24..40 | Kb 40..56 | Vt 56..72 | Ab 72..88
    char* ws = (char*)d_ws;
    unsigned short* xb    = (unsigned short*)(ws + (size_t)0  * 1024 * 1024);
    unsigned short* WqkvT = (unsigned short*)(ws + (size_t)16 * 1024 * 1024);
    unsigned short* WoutT = (unsigned short*)(ws + (size_t)22 * 1024 * 1024);
    unsigned short* Qb    = (unsigned short*)(ws + (size_t)24 * 1024 * 1024);
    unsigned short* Kb    = (unsigned short*)(ws + (size_t)40 * 1024 * 1024);
    unsigned short* Vt    = (unsigned short*)(ws + (size_t)56 * 1024 * 1024);
    unsigned short* Ab    = (unsigned short*)(ws + (size_t)72 * 1024 * 1024);

    // 0) converts / transposes
    cvt_bf16<<<dim3(MROWS * DMODEL / 1024), 256, 0, stream>>>(x, xb, MROWS * DMODEL);
    cvt_tr<<<dim3(3 * DMODEL / 32, DMODEL / 32), 256, 0, stream>>>(Wqkv, WqkvT, DMODEL, 3 * DMODEL);
    cvt_tr<<<dim3(DMODEL / 32, DMODEL / 32), 256, 0, stream>>>(Wout, WoutT, DMODEL, DMODEL);

    // 1) qkv = x @ W_qkv + b_qkv -> Qb (scaled), Kb, Vt
    gemm_mfma<<<dim3(3 * DMODEL / 128, MROWS / 128), 256, 0, stream>>>(
        xb, WqkvT, bqkv, 3 * DMODEL, DMODEL, 0, Qb, Kb, Vt, nullptr);

    // 2) causal MFMA flash attention (split-K within WG) -> Ab bf16
    attn_mfma<<<dim3(BATCH * NHEADS, 64), 256, 0, stream>>>(Qb, Kb, Vt, Ab);

    // 3) out = Ab @ W_out + b_out (fp32 out)
    gemm_mfma<<<dim3(DMODEL / 128, MROWS / 128), 256, 0, stream>>>(
        Ab, WoutT, bout, DMODEL, DMODEL, 1, nullptr, nullptr, nullptr, out);
}

// Round 10
// 397.558 us; speedup vs baseline: 1.4457x; 1.4457x over previous
//
#include <hip/hip_runtime.h>
#include <stdint.h>

#define T_SEQ   2048
#define DMODEL  1024
#define NHEADS  16
#define HDIM    64
#define BATCH   4
#define MROWS   (BATCH * T_SEQ)   // 8192

typedef __attribute__((ext_vector_type(4))) short bf16x4;
typedef __attribute__((ext_vector_type(8))) short bf16x8;
typedef __attribute__((ext_vector_type(4))) float f32x4;

__device__ __forceinline__ float b2f(unsigned short u) {
    union { unsigned int i; float f; } x;
    x.i = ((unsigned int)u) << 16;
    return x.f;
}

__device__ __forceinline__ unsigned short f2b(float f) {
    union { float f; unsigned int i; } x;
    x.f = f;
    unsigned int r = x.i + 0x7FFFu + ((x.i >> 16) & 1u);  // RNE
    return (unsigned short)(r >> 16);
}

// ---------------------------------------------------------------------------
// fp32 -> bf16 elementwise convert
// ---------------------------------------------------------------------------
__global__ __launch_bounds__(256) void cvt_bf16(
    const float* __restrict__ in, unsigned short* __restrict__ out, int n)
{
    const int i = (blockIdx.x * 256 + threadIdx.x) * 4;
    if (i + 3 < n) {
        const float4 v = *(const float4*)(in + i);
        ushort4 o;
        o.x = f2b(v.x); o.y = f2b(v.y); o.z = f2b(v.z); o.w = f2b(v.w);
        *(ushort4*)(out + i) = o;
    }
}

// ---------------------------------------------------------------------------
// fp32 [K][N] -> bf16 [N][K] transpose+convert, 32x32 LDS tile
// ---------------------------------------------------------------------------
__global__ __launch_bounds__(256) void cvt_tr(
    const float* __restrict__ W, unsigned short* __restrict__ WT, int K, int N)
{
    __shared__ unsigned short s[32][33];
    const int n0 = blockIdx.x * 32, k0 = blockIdx.y * 32;
    const int tx = threadIdx.x & 31, ty = threadIdx.x >> 5;   // ty 0..7
    #pragma unroll
    for (int i = 0; i < 4; i++)
        s[ty + 8 * i][tx] = f2b(W[(size_t)(k0 + ty + 8 * i) * N + n0 + tx]);
    __syncthreads();
    #pragma unroll
    for (int i = 0; i < 4; i++)
        WT[(size_t)(n0 + ty + 8 * i) * K + k0 + tx] = s[tx][ty + 8 * i];
}

// ---------------------------------------------------------------------------
// bf16 MFMA GEMM: C[M][N] = A[M][Kd] * BT[N][Kd]^T + bias[N]
// 128x128 tile, BK=32, 256 thr = 4 waves (2x2), each wave 64x64 = 4x4 MFMAs.
// (unchanged from R5)
// ---------------------------------------------------------------------------
__global__ __launch_bounds__(256) void gemm_mfma(
    const unsigned short* __restrict__ A,
    const unsigned short* __restrict__ BT,
    const float* __restrict__ bias,
    int N, int Kd, int mode,
    unsigned short* __restrict__ Oq,
    unsigned short* __restrict__ Ok,
    unsigned short* __restrict__ Ov,
    float* __restrict__ Of)
{
    __shared__ __align__(16) unsigned short aS[128 * 32];
    __shared__ __align__(16) unsigned short bS[128 * 32];

    const int tid  = threadIdx.x;
    const int lane = tid & 63;
    const int wave = tid >> 6;
    const int row  = lane & 15;
    const int quad = lane >> 4;
    const int wm   = wave >> 1;
    const int wn   = wave & 1;
    const int m0   = blockIdx.y * 128;
    const int n0   = blockIdx.x * 128;

    const int srow  = lane >> 2;
    const int kq    = lane & 3;
    const int sslot = (kq + (srow >> 1)) & 3;
    const int soffA = wave * 512 + srow * 32 + sslot * 8;
    const int frd = row * 32 + (((quad + (row >> 1)) & 3) * 8);

    f32x4 acc[4][4];
    const f32x4 z = {0.f, 0.f, 0.f, 0.f};
    #pragma unroll
    for (int i = 0; i < 4; i++)
        #pragma unroll
        for (int j = 0; j < 4; j++) acc[i][j] = z;

    for (int k0 = 0; k0 < Kd; k0 += 32) {
        const uint4 a0 = *(const uint4*)(A  + (size_t)(m0 + wave * 16      + srow) * Kd + k0 + kq * 8);
        const uint4 a1 = *(const uint4*)(A  + (size_t)(m0 + (wave + 4) * 16 + srow) * Kd + k0 + kq * 8);
        const uint4 b0 = *(const uint4*)(BT + (size_t)(n0 + wave * 16      + srow) * Kd + k0 + kq * 8);
        const uint4 b1 = *(const uint4*)(BT + (size_t)(n0 + (wave + 4) * 16 + srow) * Kd + k0 + kq * 8);

        __syncthreads();
        *(uint4*)(aS + soffA)        = a0;
        *(uint4*)(aS + soffA + 2048) = a1;
        *(uint4*)(bS + soffA)        = b0;
        *(uint4*)(bS + soffA + 2048) = b1;
        __syncthreads();

        bf16x8 af[4], bf[4];
        #pragma unroll
        for (int t = 0; t < 4; t++) {
            af[t] = *(const bf16x8*)(aS + (wm * 4 + t) * 512 + frd);
            bf[t] = *(const bf16x8*)(bS + (wn * 4 + t) * 512 + frd);
        }
        #pragma unroll
        for (int i = 0; i < 4; i++)
            #pragma unroll
            for (int j = 0; j < 4; j++)
                acc[i][j] = __builtin_amdgcn_mfma_f32_16x16x32_bf16(af[i], bf[j], acc[i][j], 0, 0, 0);
    }

    if (mode == 0) {
        #pragma unroll
        for (int j = 0; j < 4; j++) {
            const int n  = n0 + wn * 64 + j * 16 + row;
            const float bi = bias[n];
            const int which = n >> 10;
            const int rem   = n & 1023;
            const int h     = rem >> 6;
            const int d     = rem & 63;
            #pragma unroll
            for (int i = 0; i < 4; i++) {
                const int mbase = m0 + wm * 64 + i * 16 + quad * 4;
                #pragma unroll
                for (int r = 0; r < 4; r++) {
                    const int m = mbase + r;
                    const int b = m >> 11;
                    const int t = m & 2047;
                    const int bh = b * NHEADS + h;
                    const float v = acc[i][j][r] + bi;
                    if (which == 0) {
                        Oq[((size_t)bh * T_SEQ + t) * HDIM + d] = f2b(v * 0.125f);
                    } else if (which == 1) {
                        Ok[((size_t)bh * T_SEQ + t) * HDIM + d] = f2b(v);
                    } else {
                        Ov[((size_t)bh * HDIM + d) * T_SEQ + t] = f2b(v);
                    }
                }
            }
        }
    } else {
        #pragma unroll
        for (int j = 0; j < 4; j++) {
            const int n  = n0 + wn * 64 + j * 16 + row;
            const float bi = bias[n];
            #pragma unroll
            for (int i = 0; i < 4; i++) {
                const int mbase = m0 + wm * 64 + i * 16 + quad * 4;
                #pragma unroll
                for (int r = 0; r < 4; r++)
                    Of[(size_t)(mbase + r) * N + n] = acc[i][j][r] + bi;
            }
        }
    }
}

// ---------------------------------------------------------------------------
// MFMA flash attention, LDS-staged K/V tiles + WG-level pairing.
// WG owns q-blocks [64P, 64P+64) (L) and [64(31-P), +64) (H); wave w owns
// 16 queries of each (q0L = 64P+16w < q0H = 64(31-P)+16w). All 4 waves
// iterate the same kb; per 64-key block the WG stages K[kb..kb+64)[64] and
// VT[0..64)[kb..kb+64) into LDS with fully-contiguous global loads
// (double-buffered via register prefetch, one __syncthreads per block).
// LDS row stride 72 elems (+8 pad) -> balanced banks for b128 K-frag and
// b64 V-frag reads. Online softmax per wave = R7 numerics exactly.
// ---------------------------------------------------------------------------
__global__ __launch_bounds__(256) void attn_mfma(
    const unsigned short* __restrict__ Q,   // [bh][t][64] bf16 (scaled)
    const unsigned short* __restrict__ K,   // [bh][t][64] bf16
    const unsigned short* __restrict__ VT,  // [bh][64][T] bf16
    unsigned short* __restrict__ Out)       // [B*T][DMODEL] bf16
{
    __shared__ __align__(16) unsigned short kS[2][64 * 72];
    __shared__ __align__(16) unsigned short vS[2][64 * 72];

    const int tid  = threadIdx.x;
    const int lane = tid & 63;
    const int wave = tid >> 6;
    const int row  = lane & 15;
    const int quad = lane >> 4;

    const int bh = blockIdx.x;
    const int b  = bh >> 4;
    const int h  = bh & 15;
    const int P  = blockIdx.y;                 // 0..15
    const int q0L = 64 * P + 16 * wave;
    const int q0H = 64 * (31 - P) + 16 * wave;
    const int kend = 64 * (31 - P) + 64;       // WG-uniform loop bound

    const size_t qkbase = (size_t)bh * T_SEQ * HDIM;
    const size_t vtbase = (size_t)bh * HDIM * T_SEQ;

    // staging geometry: pass covers 2048 elems; thread -> (krow, chunk)
    const int krow0 = tid >> 3;          // 0..31
    const int c0    = tid & 7;           // 0..7
    const int lds0  = krow0 * 72 + c0 * 8;
    const int lds1  = (krow0 + 32) * 72 + c0 * 8;
    const int flat0 = tid * 8;           // = krow0*64 + c0*8

    // Q fragments
    const unsigned short* qpL = Q + qkbase + (size_t)(q0L + row) * HDIM + quad * 8;
    const bf16x8 qL0 = *(const bf16x8*)qpL;
    const bf16x8 qL1 = *(const bf16x8*)(qpL + 32);
    const unsigned short* qpH = Q + qkbase + (size_t)(q0H + row) * HDIM + quad * 8;
    const bf16x8 qH0 = *(const bf16x8*)qpH;
    const bf16x8 qH1 = *(const bf16x8*)(qpH + 32);

    const f32x4 z = {0.f, 0.f, 0.f, 0.f};
    f32x4 oL[4] = {z, z, z, z};
    f32x4 oH[4] = {z, z, z, z};
    float mL = -1e30f, lL = 0.f, mH = -1e30f, lH = 0.f;

    // prefetch tile 0
    uint4 pk0 = *(const uint4*)(K  + qkbase + flat0);
    uint4 pk1 = *(const uint4*)(K  + qkbase + flat0 + 2048);
    uint4 pv0 = *(const uint4*)(VT + vtbase + (size_t)krow0        * T_SEQ + c0 * 8);
    uint4 pv1 = *(const uint4*)(VT + vtbase + (size_t)(krow0 + 32) * T_SEQ + c0 * 8);

    int buf = 0;
    for (int kb = 0; kb < kend; kb += 64) {
        // write staged tile to LDS[buf]
        *(uint4*)&kS[buf][lds0] = pk0;
        *(uint4*)&kS[buf][lds1] = pk1;
        *(uint4*)&vS[buf][lds0] = pv0;
        *(uint4*)&vS[buf][lds1] = pv1;
        __syncthreads();

        // prefetch next tile (overlaps with compute below)
        if (kb + 64 < kend) {
            const int kn = kb + 64;
            pk0 = *(const uint4*)(K  + qkbase + (size_t)kn * HDIM + flat0);
            pk1 = *(const uint4*)(K  + qkbase + (size_t)kn * HDIM + flat0 + 2048);
            pv0 = *(const uint4*)(VT + vtbase + (size_t)krow0        * T_SEQ + kn + c0 * 8);
            pv1 = *(const uint4*)(VT + vtbase + (size_t)(krow0 + 32) * T_SEQ + kn + c0 * 8);
        }

        const bool blkL = (kb <= q0L);       // wave-uniform

        // ---- QK^T from LDS K tile ----
        f32x4 sH[4], sL[4];
        #pragma unroll
        for (int s = 0; s < 4; s++) {
            const int kbs = kb + s * 16;
            const bool needH = (kbs <= q0H);
            const bool needL = (kbs <= q0L);
            if (needH) {
                const unsigned short* kp = &kS[buf][(s * 16 + row) * 72 + quad * 8];
                const bf16x8 kf0 = *(const bf16x8*)kp;
                const bf16x8 kf1 = *(const bf16x8*)(kp + 32);
                f32x4 t = z;
                t = __builtin_amdgcn_mfma_f32_16x16x32_bf16(kf0, qH0, t, 0, 0, 0);
                t = __builtin_amdgcn_mfma_f32_16x16x32_bf16(kf1, qH1, t, 0, 0, 0);
                if (kbs == q0H) {
                    #pragma unroll
                    for (int r = 0; r < 4; r++)
                        if (quad * 4 + r > row) t[r] = -1e30f;
                }
                sH[s] = t;
                if (needL) {
                    f32x4 u = z;
                    u = __builtin_amdgcn_mfma_f32_16x16x32_bf16(kf0, qL0, u, 0, 0, 0);
                    u = __builtin_amdgcn_mfma_f32_16x16x32_bf16(kf1, qL1, u, 0, 0, 0);
                    if (kbs == q0L) {
                        #pragma unroll
                        for (int r = 0; r < 4; r++)
                            if (quad * 4 + r > row) u[r] = -1e30f;
                    }
                    sL[s] = u;
                } else {
                    #pragma unroll
                    for (int r = 0; r < 4; r++) sL[s][r] = -1e30f;
                }
            } else {
                #pragma unroll
                for (int r = 0; r < 4; r++) { sH[s][r] = -1e30f; sL[s][r] = -1e30f; }
            }
        }

        // ---- online softmax, tile H (always active: kb <= q0H holds) ----
        bf16x4 pfH[4];
        {
            float mc = -1e30f;
            #pragma unroll
            for (int s = 0; s < 4; s++)
                #pragma unroll
                for (int r = 0; r < 4; r++) mc = fmaxf(mc, sH[s][r]);
            mc = fmaxf(mc, __shfl_xor(mc, 16));
            mc = fmaxf(mc, __shfl_xor(mc, 32));
            const float mn    = fmaxf(mH, mc);
            const float alpha = __expf(mH - mn);
            float ps = 0.f;
            #pragma unroll
            for (int s = 0; s < 4; s++) {
                #pragma unroll
                for (int r = 0; r < 4; r++) {
                    const unsigned short pb = f2b(__expf(sH[s][r] - mn));
                    pfH[s][r] = (short)pb;
                    ps += b2f(pb);
                }
            }
            ps += __shfl_xor(ps, 16);
            ps += __shfl_xor(ps, 32);
            lH = lH * alpha + ps;
            mH = mn;
            #pragma unroll
            for (int dt = 0; dt < 4; dt++)
                #pragma unroll
                for (int r = 0; r < 4; r++) oH[dt][r] *= alpha;
        }

        // ---- online softmax, tile L ----
        bf16x4 pfL[4];
        if (blkL) {
            float mc = -1e30f;
            #pragma unroll
            for (int s = 0; s < 4; s++)
                #pragma unroll
                for (int r = 0; r < 4; r++) mc = fmaxf(mc, sL[s][r]);
            mc = fmaxf(mc, __shfl_xor(mc, 16));
            mc = fmaxf(mc, __shfl_xor(mc, 32));
            const float mn    = fmaxf(mL, mc);
            const float alpha = __expf(mL - mn);
            float ps = 0.f;
            #pragma unroll
            for (int s = 0; s < 4; s++) {
                #pragma unroll
                for (int r = 0; r < 4; r++) {
                    const unsigned short pb = f2b(__expf(sL[s][r] - mn));
                    pfL[s][r] = (short)pb;
                    ps += b2f(pb);
                }
            }
            ps += __shfl_xor(ps, 16);
            ps += __shfl_xor(ps, 32);
            lL = lL * alpha + ps;
            mL = mn;
            #pragma unroll
            for (int dt = 0; dt < 4; dt++)
                #pragma unroll
                for (int r = 0; r < 4; r++) oL[dt][r] *= alpha;
        }

        // ---- PV from LDS V^T tile ----
        #pragma unroll
        for (int s = 0; s < 4; s++) {
            const int kbs = kb + s * 16;
            if (kbs <= q0H) {
                const bool doL = (kbs <= q0L);
                #pragma unroll
                for (int dt = 0; dt < 4; dt++) {
                    const bf16x4 vf = *(const bf16x4*)&vS[buf][
                        (dt * 16 + row) * 72 + (s * 2 + (quad >> 1)) * 8 + (quad & 1) * 4];
                    oH[dt] = __builtin_amdgcn_mfma_f32_16x16x16bf16_1k(vf, pfH[s], oH[dt], 0, 0, 0);
                    if (doL)
                        oL[dt] = __builtin_amdgcn_mfma_f32_16x16x16bf16_1k(vf, pfL[s], oL[dt], 0, 0, 0);
                }
            }
        }

        buf ^= 1;
    }

    // ---- epilogue: both tiles ----
    {
        const float rl = 1.f / lH;
        unsigned short* op = Out + ((size_t)(b * T_SEQ + q0H + row)) * DMODEL + h * HDIM + quad * 4;
        #pragma unroll
        for (int dt = 0; dt < 4; dt++) {
            ushort4 pk;
            pk.x = f2b(oH[dt][0] * rl);
            pk.y = f2b(oH[dt][1] * rl);
            pk.z = f2b(oH[dt][2] * rl);
            pk.w = f2b(oH[dt][3] * rl);
            *(ushort4*)(op + dt * 16) = pk;
        }
    }
    {
        const float rl = 1.f / lL;
        unsigned short* op = Out + ((size_t)(b * T_SEQ + q0L + row)) * DMODEL + h * HDIM + quad * 4;
        #pragma unroll
        for (int dt = 0; dt < 4; dt++) {
            ushort4 pk;
            pk.x = f2b(oL[dt][0] * rl);
            pk.y = f2b(oL[dt][1] * rl);
            pk.z = f2b(oL[dt][2] * rl);
            pk.w = f2b(oL[dt][3] * rl);
            *(ushort4*)(op + dt * 16) = pk;
        }
    }
}

extern "C" void kernel_launch(void* const* d_in, const int* in_sizes, int n_in,
                              void* d_out, int out_size, void* d_ws, size_t ws_size,
                              hipStream_t stream)
{
    const float* x    = (const float*)d_in[0];
    const float* Wqkv = (const float*)d_in[1];
    const float* bqkv = (const float*)d_in[2];
    const float* Wout = (const float*)d_in[3];
    const float* bout = (const float*)d_in[4];
    float* out = (float*)d_out;

    // workspace (MiB offsets): xb 0..16 | WqkvT 16..22 | WoutT 22..24 |
    // Qb 24..40 | Kb 40..56 | Vt 56..72 | Ab 72..88
    char* ws = (char*)d_ws;
    unsigned short* xb    = (unsigned short*)(ws + (size_t)0  * 1024 * 1024);
    unsigned short* WqkvT = (unsigned short*)(ws + (size_t)16 * 1024 * 1024);
    unsigned short* WoutT = (unsigned short*)(ws + (size_t)22 * 1024 * 1024);
    unsigned short* Qb    = (unsigned short*)(ws + (size_t)24 * 1024 * 1024);
    unsigned short* Kb    = (unsigned short*)(ws + (size_t)40 * 1024 * 1024);
    unsigned short* Vt    = (unsigned short*)(ws + (size_t)56 * 1024 * 1024);
    unsigned short* Ab    = (unsigned short*)(ws + (size_t)72 * 1024 * 1024);

    // 0) converts / transposes
    cvt_bf16<<<dim3(MROWS * DMODEL / 1024), 256, 0, stream>>>(x, xb, MROWS * DMODEL);
    cvt_tr<<<dim3(3 * DMODEL / 32, DMODEL / 32), 256, 0, stream>>>(Wqkv, WqkvT, DMODEL, 3 * DMODEL);
    cvt_tr<<<dim3(DMODEL / 32, DMODEL / 32), 256, 0, stream>>>(Wout, WoutT, DMODEL, DMODEL);

    // 1) qkv = x @ W_qkv + b_qkv -> Qb (scaled), Kb, Vt
    gemm_mfma<<<dim3(3 * DMODEL / 128, MROWS / 128), 256, 0, stream>>>(
        xb, WqkvT, bqkv, 3 * DMODEL, DMODEL, 0, Qb, Kb, Vt, nullptr);

    // 2) causal MFMA flash attention (LDS-staged K/V) -> Ab bf16
    attn_mfma<<<dim3(BATCH * NHEADS, 16), 256, 0, stream>>>(Qb, Kb, Vt, Ab);

    // 3) out = Ab @ W_out + b_out (fp32 out)
    gemm_mfma<<<dim3(DMODEL / 128, MROWS / 128), 256, 0, stream>>>(
        Ab, WoutT, bout, DMODEL, DMODEL, 1, nullptr, nullptr, nullptr, out);
}